// Round 1
// baseline (644.923 us; speedup 1.0000x reference)
//
#include <hip/hip_runtime.h>
#include <cstdint>
#include <cstddef>

#define N_ENT 100000
#define DIM 128
#define BSZ 256
#define FSZ 20000

// ---------------- ws layout ----------------
// qall : [512][128] f32  (j<256: q_b = e_r - e_t ; j>=256: -p_b = -(e_h + e_r))
// qsq  : [512] f32       (||q_b||^2 ; ||p_b||^2)
// thr  : [512] f32       (max(triple_sq_b, eps), duplicated for both sides)
// cnt  : [512] int       (unfiltered counts, head side then tail side)
#define WS_QALL 0
#define WS_QSQ  (512 * DIM * 4)
#define WS_THR  (WS_QSQ + 512 * 4)
#define WS_CNT  (WS_THR + 512 * 4)

__global__ __launch_bounds__(128) void k_prep(
    const float* __restrict__ ent, const float* __restrict__ rel,
    const int* __restrict__ heads, const int* __restrict__ rels, const int* __restrict__ tails,
    float* __restrict__ qall, float* __restrict__ qsq, float* __restrict__ thr,
    int* __restrict__ cnt)
{
    int b = blockIdx.x;
    int d = threadIdx.x;
    int h = heads[b], r = rels[b], t = tails[b];
    float eh = ent[(size_t)h * DIM + d];
    float er = rel[(size_t)r * DIM + d];
    float et = ent[(size_t)t * DIM + d];
    float diff = eh + er - et;
    float q = er - et;
    float p = eh + er;
    qall[(size_t)b * DIM + d] = q;
    qall[(size_t)(BSZ + b) * DIM + d] = -p;   // fold the minus sign of the tail side
    float s0 = diff * diff, s1 = q * q, s2 = p * p;
    #pragma unroll
    for (int off = 32; off; off >>= 1) {
        s0 += __shfl_xor(s0, off);
        s1 += __shfl_xor(s1, off);
        s2 += __shfl_xor(s2, off);
    }
    __shared__ float part[2][3];
    int wave = threadIdx.x >> 6, lane = threadIdx.x & 63;
    if (lane == 0) { part[wave][0] = s0; part[wave][1] = s1; part[wave][2] = s2; }
    __syncthreads();
    if (threadIdx.x == 0) {
        float tsq = part[0][0] + part[1][0];
        float qq  = part[0][1] + part[1][1];
        float pp  = part[0][2] + part[1][2];
        float th = fmaxf(tsq, 1e-12f);
        thr[b] = th; thr[BSZ + b] = th;
        qsq[b] = qq; qsq[BSZ + b] = pp;
        cnt[b] = 0;  cnt[BSZ + b] = 0;
    }
}

// Each thread owns one entity row (32 float4 in registers); 64-query chunks
// staged in LDS; condition counted via wave ballot -> LDS counters -> global.
__global__ __launch_bounds__(256, 2) void k_count(
    const float* __restrict__ ent,
    const float* __restrict__ qall, const float* __restrict__ qsq,
    const float* __restrict__ thr, int* __restrict__ cnt)
{
    __shared__ float qbuf[64 * DIM];
    __shared__ float qsq_c[64], thr_c[64];
    __shared__ int lcnt[512];
    int tid = threadIdx.x;
    long n = (long)blockIdx.x * 256 + tid;
    bool valid = (n < N_ENT);
    const float4* erow = (const float4*)(ent + (size_t)(valid ? n : 0) * DIM);
    float4 e[32];
    float esq = 0.f;
    #pragma unroll
    for (int i = 0; i < 32; i++) {
        e[i] = erow[i];
        esq += e[i].x * e[i].x + e[i].y * e[i].y + e[i].z * e[i].z + e[i].w * e[i].w;
    }
    for (int i = tid; i < 512; i += 256) lcnt[i] = 0;

    for (int c = 0; c < 8; c++) {
        __syncthreads();
        const float4* src = (const float4*)(qall + (size_t)c * 64 * DIM);
        float4* dst = (float4*)qbuf;
        #pragma unroll
        for (int k = 0; k < 8; k++) dst[tid + k * 256] = src[tid + k * 256];
        if (tid < 64) { qsq_c[tid] = qsq[c * 64 + tid]; thr_c[tid] = thr[c * 64 + tid]; }
        __syncthreads();
        for (int j = 0; j < 64; j++) {
            const float4* qv = (const float4*)(qbuf + j * DIM);  // wave-uniform: broadcast
            float a0 = 0.f, a1 = 0.f, a2 = 0.f, a3 = 0.f;
            #pragma unroll
            for (int i = 0; i < 32; i += 4) {
                float4 v0 = qv[i], v1 = qv[i + 1], v2 = qv[i + 2], v3 = qv[i + 3];
                a0 += e[i    ].x * v0.x + e[i    ].y * v0.y + e[i    ].z * v0.z + e[i    ].w * v0.w;
                a1 += e[i + 1].x * v1.x + e[i + 1].y * v1.y + e[i + 1].z * v1.z + e[i + 1].w * v1.w;
                a2 += e[i + 2].x * v2.x + e[i + 2].y * v2.y + e[i + 2].z * v2.z + e[i + 2].w * v2.w;
                a3 += e[i + 3].x * v3.x + e[i + 3].y * v3.y + e[i + 3].z * v3.z + e[i + 3].w * v3.w;
            }
            float dot = (a0 + a1) + (a2 + a3);
            float sq = esq + 2.f * dot + qsq_c[j];
            bool cond = valid && (fmaxf(sq, 1e-12f) < thr_c[j]);
            unsigned long long bal = __ballot(cond);
            if ((tid & 63) == 0) atomicAdd(&lcnt[c * 64 + j], (int)__popcll(bal));
        }
    }
    __syncthreads();
    for (int i = tid; i < 512; i += 256)
        if (lcnt[i]) atomicAdd(&cnt[i], lcnt[i]);
}

// Per-b: scan filter triples, collect matching corrupted-entity ids, dedup,
// subtract those that would have counted, write rank = cnt + 1 - adj.
__global__ __launch_bounds__(256) void k_finalize(
    const float* __restrict__ ent,
    const int* __restrict__ heads, const int* __restrict__ rels, const int* __restrict__ tails,
    const int* __restrict__ fh, const int* __restrict__ fr, const int* __restrict__ ft,
    const float* __restrict__ qall, const float* __restrict__ qsq, const float* __restrict__ thr,
    const int* __restrict__ cnt, int* __restrict__ out)
{
    int b = blockIdx.x;
    int tid = threadIdx.x;
    int h = heads[b], r = rels[b], t = tails[b];
    __shared__ int m;
    __shared__ int ids[2048];
    for (int side = 0; side < 2; side++) {
        __syncthreads();
        if (tid == 0) m = 0;
        __syncthreads();
        for (int f = tid; f < FSZ; f += 256) {
            bool match = (side == 0) ? (fr[f] == r && ft[f] == t)
                                     : (fr[f] == r && fh[f] == h);
            if (match) {
                int pos = atomicAdd(&m, 1);
                if (pos < 2048) ids[pos] = (side == 0) ? fh[f] : ft[f];
            }
        }
        __syncthreads();
        if (tid == 0) {
            int mm = m < 2048 ? m : 2048;
            int adj = 0;
            const float* qv = qall + (size_t)(side * BSZ + b) * DIM;
            float qq = qsq[side * BSZ + b];
            float th = thr[side * BSZ + b];
            for (int i = 0; i < mm; i++) {
                int id = ids[i];
                bool dup = false;
                for (int jj = 0; jj < i; jj++) if (ids[jj] == id) { dup = true; break; }
                if (dup) continue;
                const float* en = ent + (size_t)id * DIM;
                float es = 0.f, dot = 0.f;
                for (int d2 = 0; d2 < DIM; d2++) { float v = en[d2]; es += v * v; dot += v * qv[d2]; }
                float sq = es + 2.f * dot + qq;
                if (fmaxf(sq, 1e-12f) < th) adj++;
            }
            out[side * BSZ + b] = cnt[side * BSZ + b] + 1 - adj;
        }
    }
}

extern "C" void kernel_launch(void* const* d_in, const int* in_sizes, int n_in,
                              void* d_out, int out_size, void* d_ws, size_t ws_size,
                              hipStream_t stream)
{
    const float* ent   = (const float*)d_in[0];
    const float* rel   = (const float*)d_in[1];
    const int*   heads = (const int*)d_in[2];
    const int*   rels  = (const int*)d_in[3];
    const int*   tails = (const int*)d_in[4];
    const int*   fh    = (const int*)d_in[5];
    const int*   fr    = (const int*)d_in[6];
    const int*   ft    = (const int*)d_in[7];
    int* out = (int*)d_out;

    char* ws = (char*)d_ws;
    float* qall = (float*)(ws + WS_QALL);
    float* qsq  = (float*)(ws + WS_QSQ);
    float* thr  = (float*)(ws + WS_THR);
    int*   cnt  = (int*)(ws + WS_CNT);

    k_prep<<<BSZ, 128, 0, stream>>>(ent, rel, heads, rels, tails, qall, qsq, thr, cnt);
    k_count<<<(N_ENT + 255) / 256, 256, 0, stream>>>(ent, qall, qsq, thr, cnt);
    k_finalize<<<BSZ, 256, 0, stream>>>(ent, heads, rels, tails, fh, fr, ft,
                                        qall, qsq, thr, cnt, out);
}

// Round 2
// 107.439 us; speedup vs baseline: 6.0027x; 6.0027x over previous
//
#include <hip/hip_runtime.h>
#include <hip/hip_bf16.h>
#include <cstdint>
#include <cstddef>

#define N_ENT 100000
#define DIM 128
#define BSZ 256
#define FSZ 20000
#define BM 64

typedef __attribute__((ext_vector_type(8))) short bf16x8;
typedef __attribute__((ext_vector_type(4))) float f32x4;

// ---------------- ws layout ----------------
// qall : [512][128] f32  (j<256: q_b = e_r - e_t ; j>=256: -p_b = -(e_h + e_r))
// qsq  : [512] f32
// thr  : [512] f32
// cnt  : [512] int
// qbf  : [512][128] bf16 (ushort)
#define WS_QALL 0
#define WS_QSQ  (512 * DIM * 4)
#define WS_THR  (WS_QSQ + 512 * 4)
#define WS_CNT  (WS_THR + 512 * 4)
#define WS_QBF  (WS_CNT + 512 * 4)

__device__ inline unsigned short f2bf(float x) {
    union { float f; uint32_t u; } v; v.f = x;
    uint32_t u = v.u;
    u += 0x7fffu + ((u >> 16) & 1);   // round-to-nearest-even
    return (unsigned short)(u >> 16);
}

__global__ __launch_bounds__(128) void k_prep(
    const float* __restrict__ ent, const float* __restrict__ rel,
    const int* __restrict__ heads, const int* __restrict__ rels, const int* __restrict__ tails,
    float* __restrict__ qall, float* __restrict__ qsq, float* __restrict__ thr,
    int* __restrict__ cnt, unsigned short* __restrict__ qbf)
{
    int b = blockIdx.x;
    int d = threadIdx.x;
    int h = heads[b], r = rels[b], t = tails[b];
    float eh = ent[(size_t)h * DIM + d];
    float er = rel[(size_t)r * DIM + d];
    float et = ent[(size_t)t * DIM + d];
    float diff = eh + er - et;
    float q = er - et;
    float p = eh + er;
    qall[(size_t)b * DIM + d] = q;
    qall[(size_t)(BSZ + b) * DIM + d] = -p;
    qbf[(size_t)b * DIM + d] = f2bf(q);
    qbf[(size_t)(BSZ + b) * DIM + d] = f2bf(-p);
    float s0 = diff * diff, s1 = q * q, s2 = p * p;
    #pragma unroll
    for (int off = 32; off; off >>= 1) {
        s0 += __shfl_xor(s0, off);
        s1 += __shfl_xor(s1, off);
        s2 += __shfl_xor(s2, off);
    }
    __shared__ float part[2][3];
    int wave = threadIdx.x >> 6, lane = threadIdx.x & 63;
    if (lane == 0) { part[wave][0] = s0; part[wave][1] = s1; part[wave][2] = s2; }
    __syncthreads();
    if (threadIdx.x == 0) {
        float tsq = part[0][0] + part[1][0];
        float qq  = part[0][1] + part[1][1];
        float pp  = part[0][2] + part[1][2];
        float th = fmaxf(tsq, 1e-12f);
        thr[b] = th; thr[BSZ + b] = th;
        qsq[b] = qq; qsq[BSZ + b] = pp;
        cnt[b] = 0;  cnt[BSZ + b] = 0;
    }
}

// MFMA count kernel: block = 4 waves, 64-entity tile vs all 512 queries.
// A (entities) fp32->bf16 converted into XOR-swizzled LDS, held in VGPRs.
// B (queries) bf16 fragments from L2-hot ws buffer, 1-chunk prefetch.
// Count per column via per-lane counter + shfl reduce + 1 atomic/col/block.
__global__ __launch_bounds__(256, 2) void k_count(
    const float* __restrict__ ent,
    const unsigned short* __restrict__ qbf,
    const float* __restrict__ qsq, const float* __restrict__ thr,
    int* __restrict__ cnt)
{
    __shared__ __align__(16) char alds[BM * 256];   // 64 rows x 128 bf16, 16B-slot swizzle
    __shared__ float esq_lds[BM];
    int tid = threadIdx.x;
    int lane = tid & 63, wave = tid >> 6;
    int base = blockIdx.x * BM;

    if (tid < BM) esq_lds[tid] = (base + tid < N_ENT) ? 0.f : 3.0e38f;
    __syncthreads();

    // stage A: 64 rows x 32 float4, convert to bf16, swizzled ds_write
    #pragma unroll
    for (int i = 0; i < 8; i++) {
        int idx = tid + i * 256;
        int row = idx >> 5, k4 = idx & 31;
        int n = base + row;
        float4 v = make_float4(0.f, 0.f, 0.f, 0.f);
        if (n < N_ENT) v = ((const float4*)ent)[(size_t)n * 32 + k4];
        float ssq = v.x * v.x + v.y * v.y + v.z * v.z + v.w * v.w;
        if (n < N_ENT) atomicAdd(&esq_lds[row], ssq);
        uint2 w2;
        w2.x = (uint32_t)f2bf(v.x) | ((uint32_t)f2bf(v.y) << 16);
        w2.y = (uint32_t)f2bf(v.z) | ((uint32_t)f2bf(v.w) << 16);
        int slot = k4 >> 1;
        int byte = row * 256 + (((slot << 4) ^ ((row & 7) << 4)) | ((k4 & 1) << 3));
        *(uint2*)(alds + byte) = w2;
    }
    __syncthreads();

    // A fragments: a[sub][kstep], row = sub*16 + (lane&15), k = kstep*32 + (lane>>4)*8
    bf16x8 a[4][4];
    #pragma unroll
    for (int s = 0; s < 4; s++) {
        #pragma unroll
        for (int ks = 0; ks < 4; ks++) {
            int row = s * 16 + (lane & 15);
            int kbyte = ks * 64 + (lane >> 4) * 16;
            a[s][ks] = *(const bf16x8*)(alds + row * 256 + (kbyte ^ ((row & 7) << 4)));
        }
    }

    int colq = wave * 128 + (lane & 15);   // this wave's column for chunk 0
    int koff = (lane >> 4) * 8;

    bf16x8 bcur[4], bnext[4];
    #pragma unroll
    for (int ks = 0; ks < 4; ks++)
        bcur[ks] = *(const bf16x8*)(qbf + (size_t)colq * DIM + ks * 32 + koff);

    #pragma unroll
    for (int c = 0; c < 8; c++) {
        if (c < 7) {
            int coln = colq + (c + 1) * 16;
            #pragma unroll
            for (int ks = 0; ks < 4; ks++)
                bnext[ks] = *(const bf16x8*)(qbf + (size_t)coln * DIM + ks * 32 + koff);
        }
        f32x4 acc[4];
        #pragma unroll
        for (int s = 0; s < 4; s++) acc[s] = (f32x4){0.f, 0.f, 0.f, 0.f};
        #pragma unroll
        for (int ks = 0; ks < 4; ks++) {
            #pragma unroll
            for (int s = 0; s < 4; s++)
                acc[s] = __builtin_amdgcn_mfma_f32_16x16x32_bf16(a[s][ks], bcur[ks], acc[s], 0, 0, 0);
        }
        int col = colq + c * 16;
        float qs = qsq[col], th = thr[col];
        int cl = 0;
        #pragma unroll
        for (int s = 0; s < 4; s++) {
            #pragma unroll
            for (int r = 0; r < 4; r++) {
                float esq_v = esq_lds[s * 16 + (lane >> 4) * 4 + r];
                float sq = esq_v + 2.f * acc[s][r] + qs;
                cl += (fmaxf(sq, 1e-12f) < th) ? 1 : 0;
            }
        }
        cl += __shfl_xor(cl, 16);
        cl += __shfl_xor(cl, 32);
        if (lane < 16) atomicAdd(&cnt[col], cl);
        #pragma unroll
        for (int ks = 0; ks < 4; ks++) bcur[ks] = bnext[ks];
    }
}

// Per-b: scan filter triples, dedup matches, exact fp32 recompute, subtract.
__global__ __launch_bounds__(256) void k_finalize(
    const float* __restrict__ ent,
    const int* __restrict__ heads, const int* __restrict__ rels, const int* __restrict__ tails,
    const int* __restrict__ fh, const int* __restrict__ fr, const int* __restrict__ ft,
    const float* __restrict__ qall, const float* __restrict__ qsq, const float* __restrict__ thr,
    const int* __restrict__ cnt, int* __restrict__ out)
{
    int b = blockIdx.x;
    int tid = threadIdx.x;
    int h = heads[b], r = rels[b], t = tails[b];
    __shared__ int m;
    __shared__ int ids[2048];
    for (int side = 0; side < 2; side++) {
        __syncthreads();
        if (tid == 0) m = 0;
        __syncthreads();
        for (int f = tid; f < FSZ; f += 256) {
            bool match = (side == 0) ? (fr[f] == r && ft[f] == t)
                                     : (fr[f] == r && fh[f] == h);
            if (match) {
                int pos = atomicAdd(&m, 1);
                if (pos < 2048) ids[pos] = (side == 0) ? fh[f] : ft[f];
            }
        }
        __syncthreads();
        if (tid == 0) {
            int mm = m < 2048 ? m : 2048;
            int adj = 0;
            const float* qv = qall + (size_t)(side * BSZ + b) * DIM;
            float qq = qsq[side * BSZ + b];
            float th = thr[side * BSZ + b];
            for (int i = 0; i < mm; i++) {
                int id = ids[i];
                bool dup = false;
                for (int jj = 0; jj < i; jj++) if (ids[jj] == id) { dup = true; break; }
                if (dup) continue;
                const float* en = ent + (size_t)id * DIM;
                float es = 0.f, dot = 0.f;
                for (int d2 = 0; d2 < DIM; d2++) { float v = en[d2]; es += v * v; dot += v * qv[d2]; }
                float sq = es + 2.f * dot + qq;
                if (fmaxf(sq, 1e-12f) < th) adj++;
            }
            out[side * BSZ + b] = cnt[side * BSZ + b] + 1 - adj;
        }
    }
}

extern "C" void kernel_launch(void* const* d_in, const int* in_sizes, int n_in,
                              void* d_out, int out_size, void* d_ws, size_t ws_size,
                              hipStream_t stream)
{
    const float* ent   = (const float*)d_in[0];
    const float* rel   = (const float*)d_in[1];
    const int*   heads = (const int*)d_in[2];
    const int*   rels  = (const int*)d_in[3];
    const int*   tails = (const int*)d_in[4];
    const int*   fh    = (const int*)d_in[5];
    const int*   fr    = (const int*)d_in[6];
    const int*   ft    = (const int*)d_in[7];
    int* out = (int*)d_out;

    char* ws = (char*)d_ws;
    float* qall = (float*)(ws + WS_QALL);
    float* qsq  = (float*)(ws + WS_QSQ);
    float* thr  = (float*)(ws + WS_THR);
    int*   cnt  = (int*)(ws + WS_CNT);
    unsigned short* qbf = (unsigned short*)(ws + WS_QBF);

    k_prep<<<BSZ, 128, 0, stream>>>(ent, rel, heads, rels, tails, qall, qsq, thr, cnt, qbf);
    k_count<<<(N_ENT + BM - 1) / BM, 256, 0, stream>>>(ent, qbf, qsq, thr, cnt);
    k_finalize<<<BSZ, 256, 0, stream>>>(ent, heads, rels, tails, fh, fr, ft,
                                        qall, qsq, thr, cnt, out);
}

// Round 3
// 91.485 us; speedup vs baseline: 7.0495x; 1.1744x over previous
//
#include <hip/hip_runtime.h>
#include <cstdint>
#include <cstddef>

#define N_ENT 100000
#define DIM 128
#define BSZ 256
#define FSZ 20000
#define BM 64
#define MCAP 8192

typedef __attribute__((ext_vector_type(8))) short bf16x8;
typedef __attribute__((ext_vector_type(4))) float f32x4;

// ---------------- ws layout ----------------
#define WS_QALL 0                               // [512][128] f32 (exact q / -p for adjust)
#define WS_QSQ  (512 * DIM * 4)                 // [512] f32
#define WS_THR  (WS_QSQ + 512 * 4)              // [512] f32
#define WS_THC  (WS_THR + 512 * 4)              // [512] f32  (thr - qsq) * 0.5
#define WS_CNT  (WS_THC + 512 * 4)              // [512] int
#define WS_MCNT (WS_CNT + 512 * 4)              // [1] int + pad
#define WS_MATCH (WS_MCNT + 16)                 // [MCAP] int2 {key=side*256+b, id}
#define WS_QBF  (WS_MATCH + MCAP * 8)           // [512][128] bf16 (16B aligned)

__device__ inline unsigned short f2bf(float x) {
    union { float f; uint32_t u; } v; v.f = x;
    uint32_t u = v.u;
    u += 0x7fffu + ((u >> 16) & 1);   // RNE
    return (unsigned short)(u >> 16);
}

__global__ __launch_bounds__(128) void k_prep(
    const float* __restrict__ ent, const float* __restrict__ rel,
    const int* __restrict__ heads, const int* __restrict__ rels, const int* __restrict__ tails,
    float* __restrict__ qall, float* __restrict__ qsq, float* __restrict__ thr,
    float* __restrict__ thc, int* __restrict__ cnt, int* __restrict__ mcnt,
    unsigned short* __restrict__ qbf)
{
    int b = blockIdx.x;
    int d = threadIdx.x;
    if (b == 0 && d == 0) *mcnt = 0;
    int h = heads[b], r = rels[b], t = tails[b];
    float eh = ent[(size_t)h * DIM + d];
    float er = rel[(size_t)r * DIM + d];
    float et = ent[(size_t)t * DIM + d];
    float diff = eh + er - et;
    float q = er - et;
    float p = eh + er;
    qall[(size_t)b * DIM + d] = q;
    qall[(size_t)(BSZ + b) * DIM + d] = -p;
    qbf[(size_t)b * DIM + d] = f2bf(q);
    qbf[(size_t)(BSZ + b) * DIM + d] = f2bf(-p);
    float s0 = diff * diff, s1 = q * q, s2 = p * p;
    #pragma unroll
    for (int off = 32; off; off >>= 1) {
        s0 += __shfl_xor(s0, off);
        s1 += __shfl_xor(s1, off);
        s2 += __shfl_xor(s2, off);
    }
    __shared__ float part[2][3];
    int wave = threadIdx.x >> 6, lane = threadIdx.x & 63;
    if (lane == 0) { part[wave][0] = s0; part[wave][1] = s1; part[wave][2] = s2; }
    __syncthreads();
    if (threadIdx.x == 0) {
        float tsq = part[0][0] + part[1][0];
        float qq  = part[0][1] + part[1][1];
        float pp  = part[0][2] + part[1][2];
        float th = fmaxf(tsq, 1e-12f);
        thr[b] = th; thr[BSZ + b] = th;
        qsq[b] = qq; qsq[BSZ + b] = pp;
        thc[b] = (th - qq) * 0.5f;
        thc[BSZ + b] = (th - pp) * 0.5f;
        cnt[b] = 0;  cnt[BSZ + b] = 0;
    }
}

// Filter scan: one thread per filter triple, B-side triples in LDS.
// Appends rare matches (key = side*256 + b, entity id) to a global list.
__global__ __launch_bounds__(256) void k_scanf(
    const int* __restrict__ heads, const int* __restrict__ rels, const int* __restrict__ tails,
    const int* __restrict__ fh, const int* __restrict__ fr, const int* __restrict__ ft,
    int* __restrict__ mcnt, int2* __restrict__ match)
{
    __shared__ int hh[BSZ], rr[BSZ], tt[BSZ];
    int tid = threadIdx.x;
    hh[tid] = heads[tid]; rr[tid] = rels[tid]; tt[tid] = tails[tid];
    __syncthreads();
    int f = blockIdx.x * 256 + tid;
    if (f >= FSZ) return;
    int vr = fr[f], vt = ft[f], vh = fh[f];
    for (int b = 0; b < BSZ; b++) {
        int rb = rr[b];
        if (vr == rb && vt == tt[b]) {          // head-side: exclude fh[f]
            int p = atomicAdd(mcnt, 1);
            if (p < MCAP) match[p] = make_int2(b, vh);
        }
        if (vr == rb && vh == hh[b]) {          // tail-side: exclude ft[f]
            int p = atomicAdd(mcnt, 1);
            if (p < MCAP) match[p] = make_int2(BSZ + b, vt);
        }
    }
}

// MFMA count: 64-entity tile/block, 4 waves x 128 query cols.
// Quartet staging (coalesced, shuffle esq, no atomics), XOR-swizzled LDS,
// chunk-0 B prefetch before the barrier, slim compare epilogue.
__global__ __launch_bounds__(256, 3) void k_count(
    const float* __restrict__ ent,
    const unsigned short* __restrict__ qbf,
    const float* __restrict__ thc,
    int* __restrict__ cnt)
{
    __shared__ __align__(16) char alds[BM * 256];   // 64 rows x 128 bf16, 16B-slot XOR swizzle
    __shared__ float esqh_lds[BM];                  // 0.5 * ||e_row||^2
    int tid = threadIdx.x;
    int lane = tid & 63, wave = tid >> 6;
    int base = blockIdx.x * BM;

    // chunk-0 B prefetch (independent of staging)
    int colq = wave * 128 + (lane & 15);
    const unsigned short* qb = qbf + (size_t)colq * DIM + (lane >> 4) * 8;
    bf16x8 bcur[4], bnext[4];
    #pragma unroll
    for (int ks = 0; ks < 4; ks++)
        bcur[ks] = *(const bf16x8*)(qb + ks * 32);

    // stage A: 4 threads per row, 128B each (fully coalesced)
    int row = tid >> 2, qtr = tid & 3;
    int n = base + row;
    bool valid = n < N_ENT;
    const float4* src = (const float4*)(ent + (size_t)n * DIM) + qtr * 8;
    float4 v[8];
    float ssq = 0.f;
    #pragma unroll
    for (int j = 0; j < 8; j++) {
        v[j] = valid ? src[j] : make_float4(0.f, 0.f, 0.f, 0.f);
        ssq += v[j].x * v[j].x + v[j].y * v[j].y + v[j].z * v[j].z + v[j].w * v[j].w;
    }
    ssq += __shfl_xor(ssq, 1);
    ssq += __shfl_xor(ssq, 2);
    if (qtr == 0) esqh_lds[row] = valid ? ssq * 0.5f : 1.5e38f;
    #pragma unroll
    for (int jp = 0; jp < 4; jp++) {
        uint4 w;
        w.x = (uint32_t)f2bf(v[2*jp    ].x) | ((uint32_t)f2bf(v[2*jp    ].y) << 16);
        w.y = (uint32_t)f2bf(v[2*jp    ].z) | ((uint32_t)f2bf(v[2*jp    ].w) << 16);
        w.z = (uint32_t)f2bf(v[2*jp + 1].x) | ((uint32_t)f2bf(v[2*jp + 1].y) << 16);
        w.w = (uint32_t)f2bf(v[2*jp + 1].z) | ((uint32_t)f2bf(v[2*jp + 1].w) << 16);
        int slot = qtr * 4 + jp;
        *(uint4*)(alds + row * 256 + ((slot ^ (row & 7)) << 4)) = w;
    }
    __syncthreads();

    // A fragments + half-esq registers
    bf16x8 a[4][4];
    #pragma unroll
    for (int s = 0; s < 4; s++) {
        int rr = s * 16 + (lane & 15);
        #pragma unroll
        for (int ks = 0; ks < 4; ks++) {
            int slot = ks * 4 + (lane >> 4);
            a[s][ks] = *(const bf16x8*)(alds + rr * 256 + ((slot ^ (rr & 7)) << 4));
        }
    }
    float eh[4][4];
    #pragma unroll
    for (int s = 0; s < 4; s++)
        #pragma unroll
        for (int r = 0; r < 4; r++)
            eh[s][r] = esqh_lds[s * 16 + (lane >> 4) * 4 + r];

    #pragma unroll
    for (int c = 0; c < 8; c++) {
        if (c < 7) {
            #pragma unroll
            for (int ks = 0; ks < 4; ks++)
                bnext[ks] = *(const bf16x8*)(qb + (size_t)(c + 1) * 16 * DIM + ks * 32);
        }
        f32x4 acc[4];
        #pragma unroll
        for (int s = 0; s < 4; s++) acc[s] = (f32x4){0.f, 0.f, 0.f, 0.f};
        #pragma unroll
        for (int ks = 0; ks < 4; ks++) {
            #pragma unroll
            for (int s = 0; s < 4; s++)
                acc[s] = __builtin_amdgcn_mfma_f32_16x16x32_bf16(a[s][ks], bcur[ks], acc[s], 0, 0, 0);
        }
        int col = colq + c * 16;
        float tc = thc[col];
        int cl = 0;
        #pragma unroll
        for (int s = 0; s < 4; s++) {
            #pragma unroll
            for (int r = 0; r < 4; r++)
                cl += (acc[s][r] < tc - eh[s][r]) ? 1 : 0;   // esq + 2*dot + qs < th
        }
        cl += __shfl_xor(cl, 16);
        cl += __shfl_xor(cl, 32);
        if (lane < 16) atomicAdd(&cnt[col], cl);
        #pragma unroll
        for (int ks = 0; ks < 4; ks++) bcur[ks] = bnext[ks];
    }
}

// Per (side,b): gather matches, dedup, exact fp32 recompute, rank = cnt+1-adj.
__global__ __launch_bounds__(64) void k_adjust(
    const float* __restrict__ ent,
    const float* __restrict__ qall, const float* __restrict__ qsq, const float* __restrict__ thr,
    const int* __restrict__ cnt, const int* __restrict__ mcnt, const int2* __restrict__ match,
    int* __restrict__ out)
{
    int key = blockIdx.x;
    int tid = threadIdx.x;
    __shared__ int ids[256];
    __shared__ int nm;
    if (tid == 0) nm = 0;
    __syncthreads();
    int M = *mcnt; if (M > MCAP) M = MCAP;
    for (int i = tid; i < M; i += 64) {
        int2 e = match[i];
        if (e.x == key) { int p = atomicAdd(&nm, 1); if (p < 256) ids[p] = e.y; }
    }
    __syncthreads();
    int mm = nm < 256 ? nm : 256;
    int adj = 0;
    const float* qv = qall + (size_t)key * DIM;
    float qq = qsq[key], th = thr[key];
    for (int i = tid; i < mm; i += 64) {
        int id = ids[i];
        bool dup = false;
        for (int j = 0; j < i; j++) if (ids[j] == id) { dup = true; break; }
        if (!dup) {
            const float* en = ent + (size_t)id * DIM;
            float es = 0.f, dot = 0.f;
            for (int d = 0; d < DIM; d++) { float x = en[d]; es += x * x; dot += x * qv[d]; }
            if (fmaxf(es + 2.f * dot + qq, 1e-12f) < th) adj++;
        }
    }
    #pragma unroll
    for (int off = 32; off; off >>= 1) adj += __shfl_xor(adj, off);
    if (tid == 0) out[key] = cnt[key] + 1 - adj;
}

extern "C" void kernel_launch(void* const* d_in, const int* in_sizes, int n_in,
                              void* d_out, int out_size, void* d_ws, size_t ws_size,
                              hipStream_t stream)
{
    const float* ent   = (const float*)d_in[0];
    const float* rel   = (const float*)d_in[1];
    const int*   heads = (const int*)d_in[2];
    const int*   rels  = (const int*)d_in[3];
    const int*   tails = (const int*)d_in[4];
    const int*   fh    = (const int*)d_in[5];
    const int*   fr    = (const int*)d_in[6];
    const int*   ft    = (const int*)d_in[7];
    int* out = (int*)d_out;

    char* ws = (char*)d_ws;
    float* qall = (float*)(ws + WS_QALL);
    float* qsq  = (float*)(ws + WS_QSQ);
    float* thr  = (float*)(ws + WS_THR);
    float* thc  = (float*)(ws + WS_THC);
    int*   cnt  = (int*)(ws + WS_CNT);
    int*   mcnt = (int*)(ws + WS_MCNT);
    int2*  match = (int2*)(ws + WS_MATCH);
    unsigned short* qbf = (unsigned short*)(ws + WS_QBF);

    k_prep<<<BSZ, 128, 0, stream>>>(ent, rel, heads, rels, tails,
                                    qall, qsq, thr, thc, cnt, mcnt, qbf);
    k_scanf<<<(FSZ + 255) / 256, 256, 0, stream>>>(heads, rels, tails, fh, fr, ft, mcnt, match);
    k_count<<<(N_ENT + BM - 1) / BM, 256, 0, stream>>>(ent, qbf, thc, cnt);
    k_adjust<<<2 * BSZ, 64, 0, stream>>>(ent, qall, qsq, thr, cnt, mcnt, match, out);
}